// Round 14
// baseline (103.036 us; speedup 1.0000x reference)
//
#include <hip/hip_runtime.h>

#define C2LOG2E 2.8853900817779268f   // 2*log2(e): exp(2x) = exp2(C2LOG2E*x)
#define LOG2E   1.4426950408889634f

__device__ __forceinline__ float sig2(float x) {   // 1/(exp2(x)+1)
    return __builtin_amdgcn_rcpf(__builtin_amdgcn_exp2f(x) + 1.0f);
}

// ---------------- Kernel 1: fused projections, pre-scaled by 2*log2(e) -----
// 256 threads, 8 rows/block. K rows are stored PERMUTED for interleaved
// splits: row kv -> p = (kv&3)*256 + (kv>>2), kct4 layout
// [b][p>>6][h>>2][p&63][h&3]. Split s of attn then reads the contiguous
// region p in [s*256, s*256+256) = {kv : kv mod 4 == s}.
// K-blocks with all rows >= valid_len exit early (poison is only read at
// masked positions; scores there are forced to -1e6).
__global__ __launch_bounds__(256) void proj_kernel(
    const float* __restrict__ q_in, const float* __restrict__ k_in,
    const float* __restrict__ Wq, const float* __restrict__ Wk,
    const int* __restrict__ valid_lens,
    float* __restrict__ qc, float* __restrict__ kct)
{
    __shared__ __align__(16) float x_s[8][128];     // 4 KB
    __shared__ __align__(16) float ps[4][8][128];   // 16 KB
    int tid = threadIdx.x;
    int blk = blockIdx.x;
    bool is_q = (blk < 128);
    int r0 = (is_q ? blk : blk - 128) * 8;
    int bb = r0 >> 10;
    if (!is_q) {
        int vl = valid_lens[bb];
        if ((r0 & 1023) >= vl) return;  // block-uniform: whole block exits
    }
    const float* X = (is_q ? q_in : k_in) + (size_t)r0 * 128;
    const float* W = is_q ? Wq : Wk;

    *(float4*)&x_s[tid >> 5][(tid & 31) * 4] = ((const float4*)X)[tid];
    __syncthreads();

    int hl = tid & 63;                  // column pair {hl, hl+64}
    int dq = tid >> 6;                  // d-quarter (wave-uniform)
    float a0[8] = {0,0,0,0,0,0,0,0};
    float a1[8] = {0,0,0,0,0,0,0,0};
#pragma unroll
    for (int i4 = 0; i4 < 8; ++i4) {
        int d = dq*32 + i4*4;
        float w00 = W[(d+0)*128 + hl], w01 = W[(d+0)*128 + hl + 64];
        float w10 = W[(d+1)*128 + hl], w11 = W[(d+1)*128 + hl + 64];
        float w20 = W[(d+2)*128 + hl], w21 = W[(d+2)*128 + hl + 64];
        float w30 = W[(d+3)*128 + hl], w31 = W[(d+3)*128 + hl + 64];
#pragma unroll
        for (int r = 0; r < 8; ++r) {
            float4 xv = *(const float4*)&x_s[r][d];   // wave-uniform broadcast
            a0[r] = fmaf(xv.x,w00, fmaf(xv.y,w10, fmaf(xv.z,w20, fmaf(xv.w,w30, a0[r]))));
            a1[r] = fmaf(xv.x,w01, fmaf(xv.y,w11, fmaf(xv.z,w21, fmaf(xv.w,w31, a1[r]))));
        }
    }
#pragma unroll
    for (int r = 0; r < 8; ++r) {
        ps[dq][r][hl]      = a0[r];
        ps[dq][r][hl + 64] = a1[r];
    }
    __syncthreads();

    int r  = tid >> 5;
    int c4 = (tid & 31) * 4;
    float4 s0 = *(const float4*)&ps[0][r][c4];
    float4 s1 = *(const float4*)&ps[1][r][c4];
    float4 s2 = *(const float4*)&ps[2][r][c4];
    float4 s3 = *(const float4*)&ps[3][r][c4];
    float4 v = make_float4(((s0.x+s1.x)+(s2.x+s3.x))*C2LOG2E,
                           ((s0.y+s1.y)+(s2.y+s3.y))*C2LOG2E,
                           ((s0.z+s1.z)+(s2.z+s3.z))*C2LOG2E,
                           ((s0.w+s1.w)+(s2.w+s3.w))*C2LOG2E);
    if (is_q) {
        *(float4*)&qc[(size_t)(r0 + r)*128 + c4] = v;
    } else {
        int kvl = (r0 & 1023) + r;              // kv within batch
        int p   = (kvl & 3)*256 + (kvl >> 2);   // interleaved permutation
        *(float4*)&kct[((((size_t)(bb*16 + (p >> 6)))*32 + (c4 >> 2))*64 + (p & 63))*4] = v;
    }
}

// ---------------- Kernel 2: interleaved-split scores + softmax + PV --------
// grid (64 q-tiles, 4 b, 4 splits) = 1024 blocks, 512 thr (8 waves) ->
// 4 blocks/CU, 32 waves/CU. Split s owns kv = 4j+s, j in [0,256): EVERY
// split has live kv for any vl -> perfect wave balance under masking (no
// dead blocks, no half-idle CUs). Block = (4 q, 256 interleaved kv).
// Wave w = (q-pair qh=w>>2 via readfirstlane -> scalar q loads; chunk c=w&3).
// Writes unnormalized O-partials + (m,l) per (split,row); combine merges
// (softmax merge is permutation-invariant). Dead splits/chunks produce
// m=-1e6 rows whose combine weight underflows to exactly 0.
__global__ __launch_bounds__(512, 8) void attn_split_kernel(
    const float* __restrict__ qc, const float* __restrict__ kct,
    const float* __restrict__ values, const int* __restrict__ valid_lens,
    const float* __restrict__ wv, float* __restrict__ pO, float* __restrict__ pml)
{
    __shared__ float2 e2_s[2][256];     // [qh][j] (e for 2 q)     4 KB
    __shared__ float4 po[8][4][64];     // PV wave partials       32 KB
    __shared__ float2 red_m[2][4], red_s[2][4];

    int tid  = threadIdx.x;
    int w    = __builtin_amdgcn_readfirstlane(tid) >> 6;  // wave 0..7 (SGPR)
    int lane = tid & 63;
    int b    = blockIdx.y;
    int q0   = blockIdx.x * 4;
    int s    = blockIdx.z;              // stride class: kv = 4j + s
    int vl   = valid_lens[b];
    int row0 = b*256 + q0;

    int qh = w >> 2;                    // q pair {2qh, 2qh+1} (scalar)
    int c  = w & 3;                     // j-chunk [c*64, c*64+64) (scalar)

    // q rows (2) + wv: scalar loads (SGPR base from scalar qh)
    const float4* qa4 = (const float4*)(qc + (size_t)(row0 + 2*qh)*128);
    const float4* qb4 = qa4 + 32;
    const float4* wv4 = (const float4*)wv;
    const float4* p0  = (const float4*)kct + ((size_t)(b*16 + s*4 + c))*2048 + lane;

    float a00 = 0.f, a10 = 0.f;
    if (c*256 + s < vl) {               // chunk live iff its smallest kv < vl
#pragma unroll 4
        for (int hb = 0; hb < 32; ++hb) {
            float4 wvv = wv4[hb];
            float4 qa = qa4[hb], qb = qb4[hb];
            float4 k0 = p0[(size_t)hb*64];       // one dwordx4: 4 h of this kv
            a00 = fmaf(wvv.x, sig2(qa.x + k0.x), a00);
            a10 = fmaf(wvv.x, sig2(qb.x + k0.x), a10);
            a00 = fmaf(wvv.y, sig2(qa.y + k0.y), a00);
            a10 = fmaf(wvv.y, sig2(qb.y + k0.y), a10);
            a00 = fmaf(wvv.z, sig2(qa.z + k0.z), a00);
            a10 = fmaf(wvv.z, sig2(qb.z + k0.z), a10);
            a00 = fmaf(wvv.w, sig2(qa.w + k0.w), a00);
            a10 = fmaf(wvv.w, sig2(qb.w + k0.w), a10);
        }
    }

    // ---- mask + split-local softmax (true kv = 4j + s) ----
    int j = c*64 + lane;                // local index 0..255
    bool valid = (4*j + s < vl);
    float s00 = valid ? -2.f*a00 : -1e6f;
    float s10 = valid ? -2.f*a10 : -1e6f;

    float m0 = s00, m1 = s10;
#pragma unroll
    for (int off = 32; off; off >>= 1) {
        m0 = fmaxf(m0, __shfl_xor(m0, off));
        m1 = fmaxf(m1, __shfl_xor(m1, off));
    }
    if (lane == 0) red_m[qh][c] = make_float2(m0, m1);
    __syncthreads();
    {
        float2 mm = red_m[qh][0];
#pragma unroll
        for (int cc = 1; cc < 4; ++cc) {
            float2 t = red_m[qh][cc];
            mm.x = fmaxf(mm.x, t.x); mm.y = fmaxf(mm.y, t.y);
        }
        m0 = mm.x; m1 = mm.y;
    }

    float e00 = __builtin_amdgcn_exp2f((s00 - m0) * LOG2E);
    float e10 = __builtin_amdgcn_exp2f((s10 - m1) * LOG2E);
    e2_s[qh][j] = make_float2(e00, e10);
    float l0 = e00, l1 = e10;
#pragma unroll
    for (int off = 32; off; off >>= 1) {
        l0 += __shfl_xor(l0, off);
        l1 += __shfl_xor(l1, off);
    }
    if (lane == 0) red_s[qh][c] = make_float2(l0, l1);
    __syncthreads();

    // per-row (m, l) to workspace (rows row0..row0+3)
    if (tid < 4) {
        int rqh = tid >> 1;
        float mm = -1e30f, lsum = 0.f;
#pragma unroll
        for (int cc = 0; cc < 4; ++cc) {
            float2 tm = red_m[rqh][cc];
            float2 tl = red_s[rqh][cc];
            mm   = fmaxf(mm, (tid & 1) ? tm.y : tm.x);
            lsum += (tid & 1) ? tl.y : tl.x;
        }
        *(float2*)&pml[(size_t)(s*1024 + row0 + tid)*2] = make_float2(mm, lsum);
    }

    // ---- PV over this split's valid kv (e==0 beyond vl when vl>0) ----
    int local_end = (vl == 0) ? 256 : min(256, (vl - s + 3) >> 2);
    float4 ac[4] = {{0,0,0,0},{0,0,0,0},{0,0,0,0},{0,0,0,0}};
    const float4* V4 = (const float4*)values + (size_t)b*65536 + (size_t)s*64 + lane;
#pragma unroll 2
    for (int k2 = w; k2 < local_end; k2 += 8) {
        float4 vv = V4[(size_t)k2*256];     // row 4*k2+s, coalesced 1 KB/wave
        float2 ea = e2_s[0][k2];            // (e_q0, e_q1)
        float2 eb = e2_s[1][k2];            // (e_q2, e_q3)
        ac[0].x = fmaf(ea.x, vv.x, ac[0].x); ac[0].y = fmaf(ea.x, vv.y, ac[0].y);
        ac[0].z = fmaf(ea.x, vv.z, ac[0].z); ac[0].w = fmaf(ea.x, vv.w, ac[0].w);
        ac[1].x = fmaf(ea.y, vv.x, ac[1].x); ac[1].y = fmaf(ea.y, vv.y, ac[1].y);
        ac[1].z = fmaf(ea.y, vv.z, ac[1].z); ac[1].w = fmaf(ea.y, vv.w, ac[1].w);
        ac[2].x = fmaf(eb.x, vv.x, ac[2].x); ac[2].y = fmaf(eb.x, vv.y, ac[2].y);
        ac[2].z = fmaf(eb.x, vv.z, ac[2].z); ac[2].w = fmaf(eb.x, vv.w, ac[2].w);
        ac[3].x = fmaf(eb.y, vv.x, ac[3].x); ac[3].y = fmaf(eb.y, vv.y, ac[3].y);
        ac[3].z = fmaf(eb.y, vv.z, ac[3].z); ac[3].w = fmaf(eb.y, vv.w, ac[3].w);
    }
#pragma unroll
    for (int q = 0; q < 4; ++q) po[w][q][lane] = ac[q];
    __syncthreads();

    // ---- combine 8 wave partials -> unnormalized O-partials (4 rows) ----
    int qq  = tid >> 7;                 // 0..3
    int col = (tid & 127) * 2;
    const float* pp = (const float*)po;     // [(w*4+q)*256 + col]
    float rx = 0.f, ry = 0.f;
#pragma unroll
    for (int ww = 0; ww < 8; ++ww) {
        float2 p = *(const float2*)&pp[(ww*4 + qq)*256 + col];
        rx += p.x; ry += p.y;
    }
    *(float2*)&pO[(size_t)(s*1024 + row0 + qq)*256 + col] = make_float2(rx, ry);
}

// ---------------- Kernel 3: merge the four split partials ------------------
// 256 blocks x 256 thr; block = 4 rows, thread = (row, 4 v-cols).
__global__ __launch_bounds__(256) void combine_kernel(
    const float* __restrict__ pO, const float* __restrict__ pml,
    float* __restrict__ out)
{
    int tid  = threadIdx.x;
    int row  = blockIdx.x*4 + (tid >> 6);   // 0..1023
    int lane = tid & 63;
    float2 ml[4];
    float m = -1e30f;
#pragma unroll
    for (int s = 0; s < 4; ++s) {
        ml[s] = *(const float2*)&pml[(size_t)(s*1024 + row)*2];
        m = fmaxf(m, ml[s].x);
    }
    float ws[4], denom = 0.f;
#pragma unroll
    for (int s = 0; s < 4; ++s) {
        ws[s] = __builtin_amdgcn_exp2f((ml[s].x - m) * LOG2E);
        denom = fmaf(ws[s], ml[s].y, denom);
    }
    float inv = 1.0f / denom;
    float4 o = {0,0,0,0};
#pragma unroll
    for (int s = 0; s < 4; ++s) {
        float4 os = ((const float4*)pO)[(size_t)(s*1024 + row)*64 + lane];
        o.x = fmaf(ws[s], os.x, o.x); o.y = fmaf(ws[s], os.y, o.y);
        o.z = fmaf(ws[s], os.z, o.z); o.w = fmaf(ws[s], os.w, o.w);
    }
    o.x *= inv; o.y *= inv; o.z *= inv; o.w *= inv;
    ((float4*)out)[(size_t)row*64 + lane] = o;
}

extern "C" void kernel_launch(void* const* d_in, const int* in_sizes, int n_in,
                              void* d_out, int out_size, void* d_ws, size_t ws_size,
                              hipStream_t stream)
{
    const float* queries = (const float*)d_in[0];   // [4,256,128]
    const float* keys    = (const float*)d_in[1];   // [4,1024,128]
    const float* values  = (const float*)d_in[2];   // [4,1024,256]
    const int*   vlens   = (const int*)d_in[3];     // [4]
    const float* Wq      = (const float*)d_in[4];   // [128,128]
    const float* Wk      = (const float*)d_in[5];   // [128,128]
    const float* wv      = (const float*)d_in[6];   // [128]
    float* out = (float*)d_out;                     // [4,256,256]

    float* qc  = (float*)d_ws;                      // 4*256*128    = 512 KB
    float* kct = qc  + 4*256*128;                   // 4*16*32*64*4 = 2 MB
    float* pO  = kct + 4*16*32*64*4;                // 4*1024*256   = 4 MB
    float* pml = pO  + 4*1024*256;                  // 4*1024*2     = 32 KB

    proj_kernel<<<640, 256, 0, stream>>>(queries, keys, Wq, Wk, vlens, qc, kct);
    attn_split_kernel<<<dim3(64, 4, 4), 512, 0, stream>>>(qc, kct, values, vlens, wv, pO, pml);
    combine_kernel<<<256, 256, 0, stream>>>(pO, pml, out);
}

// Round 15
// 94.859 us; speedup vs baseline: 1.0862x; 1.0862x over previous
//
#include <hip/hip_runtime.h>

#define C2LOG2E 2.8853900817779268f   // 2*log2(e): exp(2x) = exp2(C2LOG2E*x)
#define LOG2E   1.4426950408889634f

__device__ __forceinline__ float sig2(float x) {   // 1/(exp2(x)+1)
    return __builtin_amdgcn_rcpf(__builtin_amdgcn_exp2f(x) + 1.0f);
}

// ---------------- Kernel 1: fused projections, pre-scaled by 2*log2(e) -----
// 256 threads, 8 rows/block. K-blocks with all rows >= valid_len exit early
// (attn reads those rows only as benign poison in partially-masked chunks;
// those scores are masked to -1e6).
// blocks 0..127: qc rows. blocks 128..639: kct4 layout [b][c][h>>2][kv][h&3].
__global__ __launch_bounds__(256) void proj_kernel(
    const float* __restrict__ q_in, const float* __restrict__ k_in,
    const float* __restrict__ Wq, const float* __restrict__ Wk,
    const int* __restrict__ valid_lens,
    float* __restrict__ qc, float* __restrict__ kct)
{
    __shared__ __align__(16) float x_s[8][128];     // 4 KB
    __shared__ __align__(16) float ps[4][8][128];   // 16 KB
    int tid = threadIdx.x;
    int blk = blockIdx.x;
    bool is_q = (blk < 128);
    int r0 = (is_q ? blk : blk - 128) * 8;
    int bb = r0 >> 10;
    if (!is_q) {
        int vl = valid_lens[bb];
        if ((r0 & 1023) >= vl) return;  // block-uniform: whole block exits
    }
    const float* X = (is_q ? q_in : k_in) + (size_t)r0 * 128;
    const float* W = is_q ? Wq : Wk;

    *(float4*)&x_s[tid >> 5][(tid & 31) * 4] = ((const float4*)X)[tid];
    __syncthreads();

    int hl = tid & 63;                  // column pair {hl, hl+64}
    int dq = tid >> 6;                  // d-quarter (wave-uniform)
    float a0[8] = {0,0,0,0,0,0,0,0};
    float a1[8] = {0,0,0,0,0,0,0,0};
#pragma unroll
    for (int i4 = 0; i4 < 8; ++i4) {
        int d = dq*32 + i4*4;
        float w00 = W[(d+0)*128 + hl], w01 = W[(d+0)*128 + hl + 64];
        float w10 = W[(d+1)*128 + hl], w11 = W[(d+1)*128 + hl + 64];
        float w20 = W[(d+2)*128 + hl], w21 = W[(d+2)*128 + hl + 64];
        float w30 = W[(d+3)*128 + hl], w31 = W[(d+3)*128 + hl + 64];
#pragma unroll
        for (int r = 0; r < 8; ++r) {
            float4 xv = *(const float4*)&x_s[r][d];   // wave-uniform broadcast
            a0[r] = fmaf(xv.x,w00, fmaf(xv.y,w10, fmaf(xv.z,w20, fmaf(xv.w,w30, a0[r]))));
            a1[r] = fmaf(xv.x,w01, fmaf(xv.y,w11, fmaf(xv.z,w21, fmaf(xv.w,w31, a1[r]))));
        }
    }
#pragma unroll
    for (int r = 0; r < 8; ++r) {
        ps[dq][r][hl]      = a0[r];
        ps[dq][r][hl + 64] = a1[r];
    }
    __syncthreads();

    int r  = tid >> 5;
    int c4 = (tid & 31) * 4;
    float4 s0 = *(const float4*)&ps[0][r][c4];
    float4 s1 = *(const float4*)&ps[1][r][c4];
    float4 s2 = *(const float4*)&ps[2][r][c4];
    float4 s3 = *(const float4*)&ps[3][r][c4];
    float4 v = make_float4(((s0.x+s1.x)+(s2.x+s3.x))*C2LOG2E,
                           ((s0.y+s1.y)+(s2.y+s3.y))*C2LOG2E,
                           ((s0.z+s1.z)+(s2.z+s3.z))*C2LOG2E,
                           ((s0.w+s1.w)+(s2.w+s3.w))*C2LOG2E);
    if (is_q) {
        *(float4*)&qc[(size_t)(r0 + r)*128 + c4] = v;
    } else {
        int c    = (r0 & 1023) >> 6;    // 64-kv chunk
        int kvin = (r0 & 63) + r;       // kv within chunk
        *(float4*)&kct[((((size_t)(bb*16 + c))*32 + (c4 >> 2))*64 + kvin)*4] = v;
    }
}

// ---------------- Kernel 2: split-KV scores + softmax + PV partials --------
// grid (128 q-tiles, 4 b, 2 kv-splits) = 1024 blocks, 512 thr -> 4 blocks/CU.
// Block = (2 q, one 512-kv half). Wave w owns chunk s*8+w (64 kv). Writes
// unnormalized O-partial + (m, l) per (split, row); combine_kernel merges.
// Fully-masked s=1 blocks (0 < vl <= 512) write m=-1e30 and exit; combine's
// w1 = exp(m1-m) = 0 annihilates their poison l/O. vl==0 runs the uniform
// path in both splits (all scores -1e6 -> e=1), matching the reference.
__global__ __launch_bounds__(512, 8) void attn_split_kernel(
    const float* __restrict__ qc, const float* __restrict__ kct,
    const float* __restrict__ values, const int* __restrict__ valid_lens,
    const float* __restrict__ wv, float* __restrict__ pO, float* __restrict__ pml)
{
    __shared__ float2 e2_s[512];        // (e_q0, e_q1) per local kv   4 KB
    __shared__ float4 po[8][2][64];     // PV wave partials           16 KB
    __shared__ float2 red_m[8], red_s[8];

    int tid  = threadIdx.x;
    int b    = blockIdx.y;
    int q0   = blockIdx.x * 2;
    int s    = blockIdx.z;              // kv half
    int w    = tid >> 6;                // wave 0..7
    int lane = tid & 63;
    int vl   = valid_lens[b];
    int row0 = b*256 + q0;

    if (s == 1 && vl > 0 && vl <= 512) {    // whole split masked: m=-1e30, exit
        if (tid < 2) pml[(size_t)(1024 + row0 + tid)*2] = -1e30f;
        return;
    }

    const float4* qa4 = (const float4*)(qc + (size_t)row0*128);
    const float4* qb4 = qa4 + 32;
    const float4* wv4 = (const float4*)wv;
    const float4* p0  = (const float4*)kct + ((size_t)(b*16 + s*8 + w))*2048 + lane;

    float a00 = 0.f, a10 = 0.f;
    if ((s*8 + w)*64 < vl) {            // wave-uniform skip of masked chunks
#pragma unroll 4
        for (int hb = 0; hb < 32; ++hb) {
            float4 wvv = wv4[hb];
            float4 qa = qa4[hb], qb = qb4[hb];
            float4 k0 = p0[(size_t)hb*64];       // one dwordx4: 4 h of this kv
            a00 = fmaf(wvv.x, sig2(qa.x + k0.x), a00);
            a10 = fmaf(wvv.x, sig2(qb.x + k0.x), a10);
            a00 = fmaf(wvv.y, sig2(qa.y + k0.y), a00);
            a10 = fmaf(wvv.y, sig2(qb.y + k0.y), a10);
            a00 = fmaf(wvv.z, sig2(qa.z + k0.z), a00);
            a10 = fmaf(wvv.z, sig2(qb.z + k0.z), a10);
            a00 = fmaf(wvv.w, sig2(qa.w + k0.w), a00);
            a10 = fmaf(wvv.w, sig2(qb.w + k0.w), a10);
        }
    }

    // ---- mask + split-local softmax ----
    int lkv = w*64 + lane;              // local kv 0..511
    bool valid = (s*512 + lkv < vl);
    float s00 = valid ? -2.f*a00 : -1e6f;
    float s10 = valid ? -2.f*a10 : -1e6f;

    float m0 = s00, m1 = s10;
#pragma unroll
    for (int off = 32; off; off >>= 1) {
        m0 = fmaxf(m0, __shfl_xor(m0, off));
        m1 = fmaxf(m1, __shfl_xor(m1, off));
    }
    if (lane == 0) red_m[w] = make_float2(m0, m1);
    __syncthreads();
    {
        float2 mm = red_m[0];
#pragma unroll
        for (int ww = 1; ww < 8; ++ww) {
            float2 t = red_m[ww];
            mm.x = fmaxf(mm.x, t.x); mm.y = fmaxf(mm.y, t.y);
        }
        m0 = mm.x; m1 = mm.y;
    }

    float e00 = __builtin_amdgcn_exp2f((s00 - m0) * LOG2E);
    float e10 = __builtin_amdgcn_exp2f((s10 - m1) * LOG2E);
    e2_s[lkv] = make_float2(e00, e10);
    float l0 = e00, l1 = e10;
#pragma unroll
    for (int off = 32; off; off >>= 1) {
        l0 += __shfl_xor(l0, off);
        l1 += __shfl_xor(l1, off);
    }
    if (lane == 0) red_s[w] = make_float2(l0, l1);
    __syncthreads();

    // ---- PV over this split's valid kv (e==0 beyond vl when vl>0) ----
    int local_end = (vl == 0) ? 512 : min(512, vl - s*512);
    float4 ac0 = {0,0,0,0}, ac1 = {0,0,0,0};
    const float4* V4 = (const float4*)values + (size_t)b*65536 + (size_t)s*512*64 + lane;
#pragma unroll 2
    for (int k2 = w; k2 < local_end; k2 += 8) {
        float4 vv = V4[(size_t)k2*64];      // coalesced 1 KB/wave
        float2 ee = e2_s[k2];               // broadcast
        ac0.x = fmaf(ee.x, vv.x, ac0.x); ac0.y = fmaf(ee.x, vv.y, ac0.y);
        ac0.z = fmaf(ee.x, vv.z, ac0.z); ac0.w = fmaf(ee.x, vv.w, ac0.w);
        ac1.x = fmaf(ee.y, vv.x, ac1.x); ac1.y = fmaf(ee.y, vv.y, ac1.y);
        ac1.z = fmaf(ee.y, vv.z, ac1.z); ac1.w = fmaf(ee.y, vv.w, ac1.w);
    }
    po[w][0][lane] = ac0;
    po[w][1][lane] = ac1;

    // per-row (m, l) to workspace
    if (tid < 2) {
        float lsum = 0.f;
#pragma unroll
        for (int ww = 0; ww < 8; ++ww) {
            float2 t = red_s[ww];
            lsum += tid ? t.y : t.x;
        }
        float mm = tid ? m1 : m0;
        *(float2*)&pml[(size_t)(s*1024 + row0 + tid)*2] = make_float2(mm, lsum);
    }
    __syncthreads();

    // ---- combine 8 wave partials -> unnormalized O-partial ----
    int qq  = tid >> 8;                 // 0..1
    int col = tid & 255;
    const float* pp = (const float*)po;     // [(w*2+q)*256 + col]
    float r = 0.f;
#pragma unroll
    for (int ww = 0; ww < 8; ++ww) r += pp[(ww*2 + qq)*256 + col];
    pO[(size_t)(s*1024 + row0 + qq)*256 + col] = r;
}

// ---------------- Kernel 3: merge the two KV-split partials ----------------
// 256 blocks x 256 thr; block = 4 rows, thread = (row, 4 v-cols).
__global__ __launch_bounds__(256) void combine_kernel(
    const float* __restrict__ pO, const float* __restrict__ pml,
    float* __restrict__ out)
{
    int tid  = threadIdx.x;
    int row  = blockIdx.x*4 + (tid >> 6);   // 0..1023
    int lane = tid & 63;
    float2 ml0 = *(const float2*)&pml[(size_t)row*2];
    float2 ml1 = *(const float2*)&pml[(size_t)(1024 + row)*2];
    float m  = fmaxf(ml0.x, ml1.x);
    float w0 = __builtin_amdgcn_exp2f((ml0.x - m) * LOG2E);
    float w1 = __builtin_amdgcn_exp2f((ml1.x - m) * LOG2E);
    float inv = 1.0f / (w0*ml0.y + w1*ml1.y);
    float4 o0 = ((const float4*)pO)[(size_t)row*64 + lane];
    float4 o1 = ((const float4*)pO)[(size_t)(1024 + row)*64 + lane];
    float4 o;
    o.x = (w0*o0.x + w1*o1.x) * inv;
    o.y = (w0*o0.y + w1*o1.y) * inv;
    o.z = (w0*o0.z + w1*o1.z) * inv;
    o.w = (w0*o0.w + w1*o1.w) * inv;
    ((float4*)out)[(size_t)row*64 + lane] = o;
}

extern "C" void kernel_launch(void* const* d_in, const int* in_sizes, int n_in,
                              void* d_out, int out_size, void* d_ws, size_t ws_size,
                              hipStream_t stream)
{
    const float* queries = (const float*)d_in[0];   // [4,256,128]
    const float* keys    = (const float*)d_in[1];   // [4,1024,128]
    const float* values  = (const float*)d_in[2];   // [4,1024,256]
    const int*   vlens   = (const int*)d_in[3];     // [4]
    const float* Wq      = (const float*)d_in[4];   // [128,128]
    const float* Wk      = (const float*)d_in[5];   // [128,128]
    const float* wv      = (const float*)d_in[6];   // [128]
    float* out = (float*)d_out;                     // [4,256,256]

    float* qc  = (float*)d_ws;                      // 4*256*128    = 512 KB
    float* kct = qc  + 4*256*128;                   // 4*16*32*64*4 = 2 MB
    float* pO  = kct + 4*16*32*64*4;                // 2*1024*256   = 2 MB
    float* pml = pO  + 2*1024*256;                  // 2*1024*2     = 16 KB

    proj_kernel<<<640, 256, 0, stream>>>(queries, keys, Wq, Wk, vlens, qc, kct);
    attn_split_kernel<<<dim3(128, 4, 2), 512, 0, stream>>>(qc, kct, values, vlens, wv, pO, pml);
    combine_kernel<<<256, 256, 0, stream>>>(pO, pml, out);
}